// Round 12
// baseline (170.025 us; speedup 1.0000x reference)
//
#include <hip/hip_runtime.h>

// 3x3 SAME conv + bias + ReLU, N=32, Cin=Cout=256, H=W=56, fp32 in/out.
// v12 = v11 + m201-faithful 4-phase-per-K-tile interleave:
//  - Block 256co x 256px, 512 thr / 8 waves (2M x 4N), wave tile 128x64
//    (8m x 4n frags of 16x16x32), acc 128 regs.
//  - LDS 2 x (A 32KB + B 32KB) = 128KB, 1 block/CU.
//  - Per K-tile, 4 phases of 16 MFMA (ks x m-half; B reg-reused):
//    {ds_read subtile; [4 DMA at P1/P2]; barrier; lgkmcnt(0);
//     sched_barrier(0); setprio(1); 16 MFMA; setprio(0); barrier}
//    Tile boundary: s_waitcnt vmcnt(0) fused with P4's closing barrier
//    (DMAs issued P1/P2 -> ~3 phases of cover; never drained mid-tile).
//  - x pre-transformed to NHWC bf16; w repacked [co][tap*256+ci] bf16;
//    zero-page halo; v7-verified XOR swizzle; XCD-chunked block swizzle.

#define GLOBAL_AS __attribute__((address_space(1)))
#define LDS_AS __attribute__((address_space(3)))

typedef __attribute__((ext_vector_type(8))) short short8;
typedef __attribute__((ext_vector_type(4))) float f32x4;
typedef __attribute__((ext_vector_type(4))) unsigned int u32x4;

#define CIN   256
#define HWS   3136        // 56*56
#define PTOT  100352      // 32*3136
#define KTOT  2304        // CIN*9
#define WROWB 4608        // KTOT*2 bytes per weight row
#define ZPOFF 1179648     // 512B zero page
#define XTOFF 1310720     // x_t: PTOT*512 bytes
#define WSNEED (XTOFF + (size_t)PTOT * 512)

__device__ __forceinline__ unsigned short f2bf(float f) {
  unsigned u = __builtin_bit_cast(unsigned, f);
  return (unsigned short)((u + 0x7fffu + ((u >> 16) & 1u)) >> 16);  // RNE
}

// Weights OIHW fp32 -> bf16 [co][tap*256+ci]; also zero the zero-page.
__global__ void wcvt_kernel(const float* __restrict__ w, unsigned char* __restrict__ ws) {
  if (blockIdx.x == 0 && threadIdx.x < 128)
    ((unsigned*)(ws + ZPOFF))[threadIdx.x] = 0u;
  int o = blockIdx.x * 256 + threadIdx.x;
  int co = o / KTOT;
  int rr = o - co * KTOT;
  int tap = rr >> 8;
  int ci = rr & 255;
  ((unsigned short*)ws)[o] = f2bf(w[co * KTOT + ci * 9 + tap]);
}

// x NCHW fp32 -> x_t [pix_global][256ci] bf16 (NHWC), via LDS transpose.
__global__ __launch_bounds__(256) void xcvt_kernel(const float* __restrict__ x,
                                                   unsigned char* __restrict__ ws) {
  __shared__ float lt[64 * 257];
  const int pg0 = blockIdx.x * 64;       // 64-px tile, never crosses images
  const int n   = pg0 / HWS;
  const int pi0 = pg0 - n * HWS;
  const int t   = threadIdx.x;
  {
    const int px = t & 63;
    const int cg = t >> 6;               // 0..3 (wave-uniform)
    const float* xb = x + ((size_t)n * 256) * HWS + pi0 + px;
#pragma unroll 8
    for (int i = 0; i < 64; ++i) {
      const int c = i * 4 + cg;
      lt[px * 257 + c] = xb[(size_t)c * HWS];
    }
  }
  __syncthreads();
  {
    const int slot = t & 31;             // 16B slot = 8 channels (32 slots/row)
    const int pxw  = t >> 5;             // 0..7
    unsigned char* xt = ws + XTOFF;
#pragma unroll
    for (int i = 0; i < 8; ++i) {
      const int p = i * 8 + pxw;
      const float* r = &lt[p * 257 + slot * 8];
      u32x4 v;
#pragma unroll
      for (int j = 0; j < 4; ++j)
        v[j] = (unsigned)f2bf(r[2 * j]) | ((unsigned)f2bf(r[2 * j + 1]) << 16);
      *(u32x4*)(xt + (size_t)(pg0 + p) * 512 + slot * 16) = v;
    }
  }
}

__global__ __launch_bounds__(512, 2) void conv_kernel(
    const unsigned char* __restrict__ ws, const float* __restrict__ bias,
    float* __restrict__ out) {
  // LDS: buf{0,1} x (A 32KB + B 32KB)
  __shared__ __align__(16) unsigned char smem[131072];

  const unsigned char* wb = ws;
  const unsigned char* xt = ws + XTOFF;
  const unsigned char* zp = ws + ZPOFF;

  const int bid = blockIdx.x;
  const int sw  = (bid & 7) * 49 + (bid >> 3);   // XCD-chunked, bijective (392=8*49)
  const int p0  = sw * 256;                      // global pixel base

  const int t    = threadIdx.x;
  const int lane = t & 63;
  const int wave = t >> 6;     // 0..7
  const int wm   = wave & 1;   // co half (128 rows)
  const int wn   = wave >> 1;  // px quarter (64 cols)
  const int rl   = lane & 15;
  const int kq   = lane >> 4;
  const int l7   = lane & 7;

  // ---- staging lane precompute: row = op*64 + (t>>3), slot = t&7 ----
  const int srow = t >> 3;                          // 0..63
  const unsigned swzs = (unsigned)(((t & 7) * 16) ^ ((srow & 7) << 4));
  const unsigned ldsW = (unsigned)(wave * 1024);    // wave-uniform chunk

  const unsigned char* aG[4];
  long long bG[4];
  int hB[4], wBp[4];
#pragma unroll
  for (int op = 0; op < 4; ++op) {
    const int arow = op * 64 + srow;                // co row 0..255
    aG[op] = wb + (size_t)arow * WROWB + swzs;
    const int pg = p0 + op * 64 + srow;             // px row 0..255
    const int n  = pg / HWS;
    const int pi = pg - n * HWS;
    hB[op]  = pi / 56;
    wBp[op] = pi - hB[op] * 56;
    bG[op]  = (long long)pg * 512 + (long long)swzs;
  }

  f32x4 acc[8][4];
  const f32x4 zero4 = {0.f, 0.f, 0.f, 0.f};
#pragma unroll
  for (int mi = 0; mi < 8; ++mi)
#pragma unroll
    for (int ni = 0; ni < 4; ++ni) acc[mi][ni] = zero4;

  auto stageA = [&](int cq, int tap, int buf) {
    const unsigned koffA = (unsigned)(tap * 512 + cq * 128);
    unsigned char* lb = smem + buf * 65536;
#pragma unroll
    for (int op = 0; op < 4; ++op)
      __builtin_amdgcn_global_load_lds(
          (const GLOBAL_AS unsigned int*)(aG[op] + koffA),
          (LDS_AS unsigned int*)(lb + op * 8192 + ldsW), 16, 0, 0);
  };
  auto stageB = [&](int cq, int tap, int buf) {
    const int kh = tap / 3;
    const int dh = kh - 1;
    const int dw = (tap - kh * 3) - 1;
    unsigned char* lb = smem + buf * 65536;
    const long long doff = (long long)(dh * 56 + dw) * 512 + cq * 128;
#pragma unroll
    for (int op = 0; op < 4; ++op) {
      const int hh  = hB[op] + dh;
      const int wwi = wBp[op] + dw;
      const bool ok = ((unsigned)hh < 56u) && ((unsigned)wwi < 56u);
      const unsigned char* g = ok ? (xt + bG[op] + doff) : zp;
      __builtin_amdgcn_global_load_lds(
          (const GLOBAL_AS unsigned int*)g,
          (LDS_AS unsigned int*)(lb + 32768 + op * 8192 + ldsW), 16, 0, 0);
    }
  };

  // compute-phase per-lane offsets (128B rows, read XOR = store XOR)
  unsigned koff[2];
  koff[0] = (unsigned)((kq * 16) ^ (l7 << 4));
  koff[1] = (unsigned)((kq * 16 + 64) ^ (l7 << 4));
  unsigned offAm[8], offBn[4];
#pragma unroll
  for (int mi = 0; mi < 8; ++mi)
    offAm[mi] = (unsigned)((wm * 128 + mi * 16 + rl) * 128);
#pragma unroll
  for (int ni = 0; ni < 4; ++ni)
    offBn[ni] = (unsigned)((wn * 64 + ni * 16 + rl) * 128);

  // ---- prologue: stage tile 0 into buf0, drain, rendezvous ----
  stageA(0, 0, 0);
  stageB(0, 0, 0);
  asm volatile("s_waitcnt vmcnt(0)\n\ts_barrier" ::: "memory");

  int buf = 0;
#pragma unroll 1
  for (int s = 0; s < 36; ++s) {
    const bool ds = (s + 1 < 36);
    const int s1  = ds ? s + 1 : 0;
    const int ncq = s1 / 9;
    const int ntap = s1 - ncq * 9;
    const unsigned char* bA = smem + buf * 65536;
    const unsigned char* bB = bA + 32768;
    short8 av[4], bv[4];

    // ---- P1: ks0, m0-3 (+B ks0 read, A-DMA for next tile) ----
#pragma unroll
    for (int ni = 0; ni < 4; ++ni)
      bv[ni] = *(const short8*)(bB + offBn[ni] + koff[0]);
#pragma unroll
    for (int mi = 0; mi < 4; ++mi)
      av[mi] = *(const short8*)(bA + offAm[mi] + koff[0]);
    if (ds) stageA(ncq, ntap, buf ^ 1);
    __builtin_amdgcn_s_barrier();
    asm volatile("s_waitcnt lgkmcnt(0)" ::: "memory");
    __builtin_amdgcn_sched_barrier(0);
    __builtin_amdgcn_s_setprio(1);
#pragma unroll
    for (int mi = 0; mi < 4; ++mi)
#pragma unroll
      for (int ni = 0; ni < 4; ++ni)
        acc[mi][ni] = __builtin_amdgcn_mfma_f32_16x16x32_bf16(
            av[mi], bv[ni], acc[mi][ni], 0, 0, 0);
    __builtin_amdgcn_s_setprio(0);
    __builtin_amdgcn_s_barrier();

    // ---- P2: ks0, m4-7 (B reg-reused, B-DMA for next tile) ----
#pragma unroll
    for (int mi = 0; mi < 4; ++mi)
      av[mi] = *(const short8*)(bA + offAm[mi + 4] + koff[0]);
    if (ds) stageB(ncq, ntap, buf ^ 1);
    __builtin_amdgcn_s_barrier();
    asm volatile("s_waitcnt lgkmcnt(0)" ::: "memory");
    __builtin_amdgcn_sched_barrier(0);
    __builtin_amdgcn_s_setprio(1);
#pragma unroll
    for (int mi = 0; mi < 4; ++mi)
#pragma unroll
      for (int ni = 0; ni < 4; ++ni)
        acc[mi + 4][ni] = __builtin_amdgcn_mfma_f32_16x16x32_bf16(
            av[mi], bv[ni], acc[mi + 4][ni], 0, 0, 0);
    __builtin_amdgcn_s_setprio(0);
    __builtin_amdgcn_s_barrier();

    // ---- P3: ks1, m0-3 ----
#pragma unroll
    for (int ni = 0; ni < 4; ++ni)
      bv[ni] = *(const short8*)(bB + offBn[ni] + koff[1]);
#pragma unroll
    for (int mi = 0; mi < 4; ++mi)
      av[mi] = *(const short8*)(bA + offAm[mi] + koff[1]);
    __builtin_amdgcn_s_barrier();
    asm volatile("s_waitcnt lgkmcnt(0)" ::: "memory");
    __builtin_amdgcn_sched_barrier(0);
    __builtin_amdgcn_s_setprio(1);
#pragma unroll
    for (int mi = 0; mi < 4; ++mi)
#pragma unroll
      for (int ni = 0; ni < 4; ++ni)
        acc[mi][ni] = __builtin_amdgcn_mfma_f32_16x16x32_bf16(
            av[mi], bv[ni], acc[mi][ni], 0, 0, 0);
    __builtin_amdgcn_s_setprio(0);
    __builtin_amdgcn_s_barrier();

    // ---- P4: ks1, m4-7; close tile with vmcnt(0)+barrier ----
#pragma unroll
    for (int mi = 0; mi < 4; ++mi)
      av[mi] = *(const short8*)(bA + offAm[mi + 4] + koff[1]);
    __builtin_amdgcn_s_barrier();
    asm volatile("s_waitcnt lgkmcnt(0)" ::: "memory");
    __builtin_amdgcn_sched_barrier(0);
    __builtin_amdgcn_s_setprio(1);
#pragma unroll
    for (int mi = 0; mi < 4; ++mi)
#pragma unroll
      for (int ni = 0; ni < 4; ++ni)
        acc[mi + 4][ni] = __builtin_amdgcn_mfma_f32_16x16x32_bf16(
            av[mi], bv[ni], acc[mi + 4][ni], 0, 0, 0);
    __builtin_amdgcn_s_setprio(0);
    asm volatile("s_waitcnt vmcnt(0)\n\ts_barrier" ::: "memory");

    buf ^= 1;
  }

  // ---- epilogue: bias + ReLU. C/D: col=lane&15, row=(lane>>4)*4+j ----
#pragma unroll
  for (int mi = 0; mi < 8; ++mi) {
    const int row = wm * 128 + mi * 16 + kq * 4;
    float br[4];
#pragma unroll
    for (int j = 0; j < 4; ++j) br[j] = bias[row + j];
#pragma unroll
    for (int ni = 0; ni < 4; ++ni) {
      const int pgb = p0 + wn * 64 + ni * 16;     // 16-span within one image
      const int n   = pgb / HWS;
      const int pib = pgb - n * HWS;
#pragma unroll
      for (int j = 0; j < 4; ++j) {
        float v = acc[mi][ni][j] + br[j];
        out[(size_t)(n * 256 + row + j) * HWS + pib + rl] = fmaxf(v, 0.f);
      }
    }
  }
}

// Correct-but-slow fallback if workspace is too small (not expected).
__global__ void naive_kernel(const float* __restrict__ x, const float* __restrict__ w,
                             const float* __restrict__ bias, float* __restrict__ out) {
  int idx = blockIdx.x * 256 + threadIdx.x;
  if (idx >= 32 * 256 * HWS) return;
  int n  = idx / (256 * HWS);
  int r  = idx - n * 256 * HWS;
  int co = r / HWS;
  int p  = r - co * HWS;
  int h = p / 56, ww = p - h * 56;
  float s = bias[co];
  const float* xb = x + (size_t)n * 256 * HWS;
  const float* wbp = w + (size_t)co * KTOT;
  for (int ci = 0; ci < 256; ++ci) {
    const float* xc = xb + (size_t)ci * HWS;
    const float* wc = wbp + ci * 9;
    for (int kh = 0; kh < 3; ++kh) {
      int hh = h + kh - 1;
      if ((unsigned)hh >= 56u) continue;
      for (int kw = 0; kw < 3; ++kw) {
        int w2 = ww + kw - 1;
        if ((unsigned)w2 >= 56u) continue;
        s += xc[hh * 56 + w2] * wc[kh * 3 + kw];
      }
    }
  }
  out[idx] = fmaxf(s, 0.f);
}

extern "C" void kernel_launch(void* const* d_in, const int* in_sizes, int n_in,
                              void* d_out, int out_size, void* d_ws, size_t ws_size,
                              hipStream_t stream) {
  const float* x    = (const float*)d_in[0];
  const float* w    = (const float*)d_in[1];
  const float* bias = (const float*)d_in[2];
  float* out        = (float*)d_out;

  if (ws_size < WSNEED) {
    hipLaunchKernelGGL(naive_kernel, dim3((32 * 256 * HWS + 255) / 256), dim3(256),
                       0, stream, x, w, bias, out);
    return;
  }
  unsigned char* ws = (unsigned char*)d_ws;
  hipLaunchKernelGGL(wcvt_kernel, dim3(2304), dim3(256), 0, stream, w, ws);
  hipLaunchKernelGGL(xcvt_kernel, dim3(PTOT / 64), dim3(256), 0, stream, x, ws);
  hipLaunchKernelGGL(conv_kernel, dim3(392), dim3(512), 0, stream, ws, bias, out);
}